// Round 2
// baseline (1137.203 us; speedup 1.0000x reference)
//
#include <hip/hip_runtime.h>
#include <hip/hip_bf16.h>
#include <math.h>

#define TOKS 49152   // B*T
#define HD   512     // hidden
#define GN   2       // groups
#define CN   320     // codes per group
#define DN   128     // code dim
#define BM   32      // tokens per block
#define BK   32      // K-step
#define NTHR 256

// ---------------- zero the p-accumulator ----------------
__global__ void k_zero(float* pp) {
  int t = threadIdx.x;
  if (t < GN * CN) pp[t] = 0.f;
}

// ---------------- fused GEMM + epilogue ----------------
// grid: (TOKS/BM, GN); block: 256
__global__ __launch_bounds__(NTHR) void k_main(
    const float* __restrict__ x, const int* __restrict__ mask,
    const float* __restrict__ gnoise, const float* __restrict__ W,
    const float* __restrict__ bias, const float* __restrict__ cv,
    float* __restrict__ out, float* __restrict__ pp)
{
  // LDS: GEMM phase:  w_lds[BK][CN] @0 (40960 B), xs[BM][BK] @40960 (4096 B)
  //      epilogue:    lg[BM][CN]    @0 (40960 B), psum[4][CN] @40960 (5120 B)
  __shared__ __align__(16) char smem[46080];
  float* w_lds = (float*)smem;
  float* xs    = (float*)(smem + 40960);
  float* lg    = (float*)smem;
  float* psum  = (float*)(smem + 40960);

  const int m0  = blockIdx.x * BM;
  const int g   = blockIdx.y;
  const int tid = threadIdx.x;
  const int tc  = tid & 63;   // lane
  const int tr  = tid >> 6;   // wave id (0..3)
  const int r0  = tr * 8;     // 8 rows per wave

  float acc[8][5];
  #pragma unroll
  for (int i = 0; i < 8; ++i)
    #pragma unroll
    for (int j = 0; j < 5; ++j) acc[i][j] = 0.f;

  const float* Wg = W + (size_t)g * CN * HD;

  for (int k0 = 0; k0 < HD; k0 += BK) {
    __syncthreads();
    // stage W tile: [BK][CN], transposed from global [CN][HD]
    #pragma unroll
    for (int t = 0; t < 10; ++t) {
      int idx = tid + t * NTHR;      // 0..2559
      int c   = idx % CN;
      int k4  = idx / CN;            // 0..7
      float4 wv = *(const float4*)(Wg + (size_t)c * HD + k0 + k4 * 4);
      w_lds[(k4 * 4 + 0) * CN + c] = wv.x;
      w_lds[(k4 * 4 + 1) * CN + c] = wv.y;
      w_lds[(k4 * 4 + 2) * CN + c] = wv.z;
      w_lds[(k4 * 4 + 3) * CN + c] = wv.w;
    }
    // stage x tile: [BM][BK]
    {
      int r = tid >> 3, k4 = tid & 7;
      float4 xv = *(const float4*)(x + (size_t)(m0 + r) * HD + k0 + k4 * 4);
      xs[r * BK + k4 * 4 + 0] = xv.x;
      xs[r * BK + k4 * 4 + 1] = xv.y;
      xs[r * BK + k4 * 4 + 2] = xv.z;
      xs[r * BK + k4 * 4 + 3] = xv.w;
    }
    __syncthreads();
    #pragma unroll
    for (int kk = 0; kk < BK; kk += 4) {
      float xq[8][4];
      #pragma unroll
      for (int i = 0; i < 8; ++i) {
        float4 t4 = *(const float4*)&xs[(r0 + i) * BK + kk];
        xq[i][0] = t4.x; xq[i][1] = t4.y; xq[i][2] = t4.z; xq[i][3] = t4.w;
      }
      #pragma unroll
      for (int q = 0; q < 4; ++q) {
        float wv[5];
        #pragma unroll
        for (int j = 0; j < 5; ++j) wv[j] = w_lds[(kk + q) * CN + tc + 64 * j];
        #pragma unroll
        for (int i = 0; i < 8; ++i)
          #pragma unroll
          for (int j = 0; j < 5; ++j)
            acc[i][j] = fmaf(xq[i][q], wv[j], acc[i][j]);
      }
    }
  }
  __syncthreads();

  // write logits (+bias) to LDS
  float bj[5];
  #pragma unroll
  for (int j = 0; j < 5; ++j) bj[j] = bias[g * CN + tc + 64 * j];
  #pragma unroll
  for (int i = 0; i < 8; ++i)
    #pragma unroll
    for (int j = 0; j < 5; ++j)
      lg[(r0 + i) * CN + tc + 64 * j] = acc[i][j] + bj[j];
  __syncthreads();

  // epilogue: wave tr handles rows r0..r0+7; lane owns cols {tc+64j}
  float pacc[5] = {0.f, 0.f, 0.f, 0.f, 0.f};
  #pragma unroll
  for (int i = 0; i < 8; ++i) {
    const int r = r0 + i;
    const int n = m0 + r;
    const size_t grow = ((size_t)n * GN + g) * CN;
    float lv[5], gv[5];
    #pragma unroll
    for (int j = 0; j < 5; ++j) lv[j] = lg[r * CN + tc + 64 * j];
    #pragma unroll
    for (int j = 0; j < 5; ++j) gv[j] = gnoise[grow + tc + 64 * j];

    // argmax of logits+gumbel (first-index tiebreak, matches jnp.argmax)
    float bv = -3.4e38f; int bi = 1 << 30;
    #pragma unroll
    for (int j = 0; j < 5; ++j) {
      float v = lv[j] + gv[j];
      if (v > bv) { bv = v; bi = tc + 64 * j; }
    }
    for (int off = 1; off < 64; off <<= 1) {
      float ov = __shfl_xor(bv, off);
      int   oi = __shfl_xor(bi, off);
      if (ov > bv || (ov == bv && oi < bi)) { bv = ov; bi = oi; }
    }

    // plain softmax accumulated into masked-mean partial
    float mx = lv[0];
    #pragma unroll
    for (int j = 1; j < 5; ++j) mx = fmaxf(mx, lv[j]);
    for (int off = 1; off < 64; off <<= 1) mx = fmaxf(mx, __shfl_xor(mx, off));
    float e[5], s = 0.f;
    #pragma unroll
    for (int j = 0; j < 5; ++j) { e[j] = expf(lv[j] - mx); s += e[j]; }
    for (int off = 1; off < 64; off <<= 1) s += __shfl_xor(s, off);
    const float inv = 1.f / s;
    const float mlt = (mask[n] != 0) ? 1.f : 0.f;
    #pragma unroll
    for (int j = 0; j < 5; ++j) pacc[j] += mlt * e[j] * inv;

    // selected = codevector gather (one-hot contraction is exact copy)
    const float2* cvr = (const float2*)(cv + ((size_t)(g * CN + bi)) * DN);
    float2* o2 = (float2*)(out + (size_t)n * (GN * DN) + g * DN);
    o2[tc] = cvr[tc];
  }

  #pragma unroll
  for (int j = 0; j < 5; ++j) psum[tr * CN + tc + 64 * j] = pacc[j];
  __syncthreads();
  // BUGFIX (round 1): was `if (tid < CN)` with blockDim=256 < CN=320,
  // so columns 256..319 were never accumulated -> perp = 0.8*H model
  // = 201.9, error 438 (exactly what the bench showed). Strided loop now.
  for (int c = tid; c < CN; c += NTHR) {
    float s = psum[c] + psum[CN + c] + psum[2 * CN + c] + psum[3 * CN + c];
    atomicAdd(&pp[g * CN + c], s);
  }
}

// ---------------- perplexity finalize (single block, 640 threads) -------
__global__ __launch_bounds__(640) void k_final(
    const float* __restrict__ pp, const int* __restrict__ mask,
    float* __restrict__ out, int out_off)
{
  __shared__ float red[10];
  __shared__ float eL[GN * CN];
  __shared__ float perp_parts[GN];
  const int tid = threadIdx.x;

  // masked-token count
  float cnt = 0.f;
  for (int i = tid; i < TOKS; i += 640) cnt += (mask[i] != 0) ? 1.f : 0.f;
  for (int off = 1; off < 64; off <<= 1) cnt += __shfl_xor(cnt, off);
  if ((tid & 63) == 0) red[tid >> 6] = cnt;
  __syncthreads();
  float denom = 0.f;
  #pragma unroll
  for (int w = 0; w < 10; ++w) denom += red[w];
  denom = fmaxf(denom, 1.f);

  const float p = pp[tid] / denom;
  eL[tid] = p * logf(p + 1e-7f);
  __syncthreads();

  if (tid < 2 * 64) {
    const int gg = tid >> 6, ll = tid & 63;
    float s = 0.f;
    #pragma unroll
    for (int j = 0; j < 5; ++j) s += eL[gg * CN + ll + 64 * j];
    for (int off = 1; off < 64; off <<= 1) s += __shfl_xor(s, off);
    if (ll == 0) perp_parts[gg] = expf(-s);
  }
  __syncthreads();
  if (tid == 0) out[out_off] = perp_parts[0] + perp_parts[1];
}

extern "C" void kernel_launch(void* const* d_in, const int* in_sizes, int n_in,
                              void* d_out, int out_size, void* d_ws, size_t ws_size,
                              hipStream_t stream) {
  const float* x     = (const float*)d_in[0];
  const int*   mask  = (const int*)d_in[1];
  const float* gn    = (const float*)d_in[2];
  const float* W     = (const float*)d_in[3];
  const float* bias  = (const float*)d_in[4];
  const float* cv    = (const float*)d_in[5];
  float* out = (float*)d_out;
  float* pp  = (float*)d_ws;   // 640 floats

  hipLaunchKernelGGL(k_zero, dim3(1), dim3(640), 0, stream, pp);
  hipLaunchKernelGGL(k_main, dim3(TOKS / BM, GN), dim3(NTHR), 0, stream,
                     x, mask, gn, W, bias, cv, out, pp);
  hipLaunchKernelGGL(k_final, dim3(1), dim3(640), 0, stream,
                     pp, mask, out, out_size - 1);
}

// Round 3
// 664.515 us; speedup vs baseline: 1.7113x; 1.7113x over previous
//
#include <hip/hip_runtime.h>
#include <hip/hip_bf16.h>
#include <math.h>

#define TOKS 49152   // B*T
#define HD   512     // hidden
#define GN   2       // groups
#define CN   320     // codes per group
#define DN   128     // code dim
#define BM   32      // tokens per block
#define BK   32      // K-step
#define NTHR 256
#define WSTR 33      // W LDS row stride (pad 32->33: read/write both 2-way, free)

// ---------------- zero the p-accumulator ----------------
__global__ void k_zero(float* pp) {
  int t = threadIdx.x;
  if (t < GN * CN) pp[t] = 0.f;
}

// ---------------- fused GEMM + epilogue ----------------
// grid: (TOKS/BM, GN); block: 256
__global__ __launch_bounds__(NTHR) void k_main(
    const float* __restrict__ x, const int* __restrict__ mask,
    const float* __restrict__ gnoise, const float* __restrict__ W,
    const float* __restrict__ bias, const float* __restrict__ cv,
    float* __restrict__ out, float* __restrict__ pp)
{
  // LDS: GEMM phase:  w_lds[CN][WSTR] @0 (42240 B), xs[BM][BK] @42240 (4096 B)
  //      epilogue:    lg[BM][CN]      @0 (40960 B), psum[4][CN] @42240 (5120 B)
  __shared__ __align__(16) char smem[47360];
  float* w_lds = (float*)smem;             // [c][k_local], stride WSTR
  float* xs    = (float*)(smem + 42240);
  float* lg    = (float*)smem;
  float* psum  = (float*)(smem + 42240);

  const int m0  = blockIdx.x * BM;
  const int g   = blockIdx.y;
  const int tid = threadIdx.x;
  const int tc  = tid & 63;   // lane
  const int tr  = tid >> 6;   // wave id (0..3)
  const int r0  = tr * 8;     // 8 rows per wave

  float acc[8][5];
  #pragma unroll
  for (int i = 0; i < 8; ++i)
    #pragma unroll
    for (int j = 0; j < 5; ++j) acc[i][j] = 0.f;

  const float* Wg = W + (size_t)g * CN * HD;

  for (int k0 = 0; k0 < HD; k0 += BK) {
    __syncthreads();
    // stage W tile into [c][k] layout.
    // COALESCING FIX (round 2): c = idx>>3 so 8 consecutive lanes read
    // 128 B contiguous from one W row (was c = idx%CN -> 64 lanes hitting
    // 64 cache lines 2 KB apart -> the 36% VALUBusy stall).
    #pragma unroll
    for (int t = 0; t < 10; ++t) {
      int idx = tid + t * NTHR;      // 0..2559
      int c   = idx >> 3;            // 0..319
      int k4  = idx & 7;             // 0..7
      float4 wv4 = *(const float4*)(Wg + (size_t)c * HD + k0 + k4 * 4);
      float* dst = &w_lds[c * WSTR + k4 * 4];
      dst[0] = wv4.x; dst[1] = wv4.y; dst[2] = wv4.z; dst[3] = wv4.w;
    }
    // stage x tile: [BM][BK]
    {
      int r = tid >> 3, k4 = tid & 7;
      float4 xv = *(const float4*)(x + (size_t)(m0 + r) * HD + k0 + k4 * 4);
      float* dst = &xs[r * BK + k4 * 4];
      dst[0] = xv.x; dst[1] = xv.y; dst[2] = xv.z; dst[3] = xv.w;
    }
    __syncthreads();
    // per-thread W base addresses (loop-invariant; kk+q folds into ds_read offset)
    #pragma unroll
    for (int kk = 0; kk < BK; kk += 4) {
      float xq[8][4];
      #pragma unroll
      for (int i = 0; i < 8; ++i) {
        float4 t4 = *(const float4*)&xs[(r0 + i) * BK + kk];
        xq[i][0] = t4.x; xq[i][1] = t4.y; xq[i][2] = t4.z; xq[i][3] = t4.w;
      }
      #pragma unroll
      for (int q = 0; q < 4; ++q) {
        float wv[5];
        #pragma unroll
        for (int j = 0; j < 5; ++j) wv[j] = w_lds[(tc + 64 * j) * WSTR + kk + q];
        #pragma unroll
        for (int i = 0; i < 8; ++i)
          #pragma unroll
          for (int j = 0; j < 5; ++j)
            acc[i][j] = fmaf(xq[i][q], wv[j], acc[i][j]);
      }
    }
  }
  __syncthreads();

  // write logits (+bias) to LDS
  float bj[5];
  #pragma unroll
  for (int j = 0; j < 5; ++j) bj[j] = bias[g * CN + tc + 64 * j];
  #pragma unroll
  for (int i = 0; i < 8; ++i)
    #pragma unroll
    for (int j = 0; j < 5; ++j)
      lg[(r0 + i) * CN + tc + 64 * j] = acc[i][j] + bj[j];
  __syncthreads();

  // epilogue: wave tr handles rows r0..r0+7; lane owns cols {tc+64j}
  float pacc[5] = {0.f, 0.f, 0.f, 0.f, 0.f};
  #pragma unroll
  for (int i = 0; i < 8; ++i) {
    const int r = r0 + i;
    const int n = m0 + r;
    const size_t grow = ((size_t)n * GN + g) * CN;
    float lv[5], gv[5];
    #pragma unroll
    for (int j = 0; j < 5; ++j) lv[j] = lg[r * CN + tc + 64 * j];
    #pragma unroll
    for (int j = 0; j < 5; ++j) gv[j] = gnoise[grow + tc + 64 * j];

    // argmax of logits+gumbel (first-index tiebreak, matches jnp.argmax)
    float bv = -3.4e38f; int bi = 1 << 30;
    #pragma unroll
    for (int j = 0; j < 5; ++j) {
      float v = lv[j] + gv[j];
      if (v > bv) { bv = v; bi = tc + 64 * j; }
    }
    for (int off = 1; off < 64; off <<= 1) {
      float ov = __shfl_xor(bv, off);
      int   oi = __shfl_xor(bi, off);
      if (ov > bv || (ov == bv && oi < bi)) { bv = ov; bi = oi; }
    }

    // plain softmax accumulated into masked-mean partial
    float mx = lv[0];
    #pragma unroll
    for (int j = 1; j < 5; ++j) mx = fmaxf(mx, lv[j]);
    for (int off = 1; off < 64; off <<= 1) mx = fmaxf(mx, __shfl_xor(mx, off));
    float e[5], s = 0.f;
    #pragma unroll
    for (int j = 0; j < 5; ++j) { e[j] = expf(lv[j] - mx); s += e[j]; }
    for (int off = 1; off < 64; off <<= 1) s += __shfl_xor(s, off);
    const float inv = 1.f / s;
    const float mlt = (mask[n] != 0) ? 1.f : 0.f;
    #pragma unroll
    for (int j = 0; j < 5; ++j) pacc[j] += mlt * e[j] * inv;

    // selected = codevector gather (one-hot contraction is exact copy)
    const float2* cvr = (const float2*)(cv + ((size_t)(g * CN + bi)) * DN);
    float2* o2 = (float2*)(out + (size_t)n * (GN * DN) + g * DN);
    o2[tc] = cvr[tc];
  }

  #pragma unroll
  for (int j = 0; j < 5; ++j) psum[tr * CN + tc + 64 * j] = pacc[j];
  __syncthreads();
  for (int c = tid; c < CN; c += NTHR) {
    float s = psum[c] + psum[CN + c] + psum[2 * CN + c] + psum[3 * CN + c];
    atomicAdd(&pp[g * CN + c], s);
  }
}

// ---------------- perplexity finalize (single block, 640 threads) -------
__global__ __launch_bounds__(640) void k_final(
    const float* __restrict__ pp, const int* __restrict__ mask,
    float* __restrict__ out, int out_off)
{
  __shared__ float red[10];
  __shared__ float eL[GN * CN];
  __shared__ float perp_parts[GN];
  const int tid = threadIdx.x;

  // masked-token count
  float cnt = 0.f;
  for (int i = tid; i < TOKS; i += 640) cnt += (mask[i] != 0) ? 1.f : 0.f;
  for (int off = 1; off < 64; off <<= 1) cnt += __shfl_xor(cnt, off);
  if ((tid & 63) == 0) red[tid >> 6] = cnt;
  __syncthreads();
  float denom = 0.f;
  #pragma unroll
  for (int w = 0; w < 10; ++w) denom += red[w];
  denom = fmaxf(denom, 1.f);

  const float p = pp[tid] / denom;
  eL[tid] = p * logf(p + 1e-7f);
  __syncthreads();

  if (tid < 2 * 64) {
    const int gg = tid >> 6, ll = tid & 63;
    float s = 0.f;
    #pragma unroll
    for (int j = 0; j < 5; ++j) s += eL[gg * CN + ll + 64 * j];
    for (int off = 1; off < 64; off <<= 1) s += __shfl_xor(s, off);
    if (ll == 0) perp_parts[gg] = expf(-s);
  }
  __syncthreads();
  if (tid == 0) out[out_off] = perp_parts[0] + perp_parts[1];
}

extern "C" void kernel_launch(void* const* d_in, const int* in_sizes, int n_in,
                              void* d_out, int out_size, void* d_ws, size_t ws_size,
                              hipStream_t stream) {
  const float* x     = (const float*)d_in[0];
  const int*   mask  = (const int*)d_in[1];
  const float* gn    = (const float*)d_in[2];
  const float* W     = (const float*)d_in[3];
  const float* bias  = (const float*)d_in[4];
  const float* cv    = (const float*)d_in[5];
  float* out = (float*)d_out;
  float* pp  = (float*)d_ws;   // 640 floats

  hipLaunchKernelGGL(k_zero, dim3(1), dim3(640), 0, stream, pp);
  hipLaunchKernelGGL(k_main, dim3(TOKS / BM, GN), dim3(NTHR), 0, stream,
                     x, mask, gn, W, bias, cv, out, pp);
  hipLaunchKernelGGL(k_final, dim3(1), dim3(640), 0, stream,
                     pp, mask, out, out_size - 1);
}

// Round 4
// 422.667 us; speedup vs baseline: 2.6905x; 1.5722x over previous
//
#include <hip/hip_runtime.h>
#include <hip/hip_bf16.h>
#include <math.h>

#define TOKS 49152   // B*T
#define HD   512     // hidden
#define GN   2       // groups
#define CN   320     // codes per group
#define DN   128     // code dim
#define BM   32      // tokens per block
#define NTHR 256
#define LSTR 321     // lg row stride (f32) -> 2-way (free) epilogue reads
#define WSTR 33      // fallback path W LDS stride

#define WS_PP_OFF 0
#define WS_W_OFF  4096
#define WS_NEED   (4096 + 2 * (size_t)(GN * CN) * HD * 2)  // pp + wh + wl

typedef _Float16 f16x8 __attribute__((ext_vector_type(8)));
typedef float    fx4   __attribute__((ext_vector_type(4)));

// ---------------- zero the p-accumulator ----------------
__global__ void k_zero(float* pp) {
  int t = threadIdx.x;
  if (t < GN * CN) pp[t] = 0.f;
}

// ---------------- W -> (wh, wl*512) f16 split (1.25 MB, trivial) ------
__global__ __launch_bounds__(256) void k_wsplit(const float* __restrict__ W,
                                                _Float16* __restrict__ wh,
                                                _Float16* __restrict__ wl) {
  int i = (blockIdx.x * 256 + threadIdx.x) * 4;   // 320 blocks cover 640*512
  float4 w4 = *(const float4*)(W + i);
  union { _Float16 h[4]; short4 s; } uh, ul;
  float v[4] = {w4.x, w4.y, w4.z, w4.w};
  #pragma unroll
  for (int e = 0; e < 4; ++e) {
    _Float16 h = (_Float16)v[e];
    uh.h[e] = h;
    ul.h[e] = (_Float16)((v[e] - (float)h) * 512.f);  // exact sub, pow2 scale
  }
  *(short4*)(wh + i) = uh.s;
  *(short4*)(wl + i) = ul.s;
}

// ---------------- fused MFMA GEMM + epilogue ----------------
// grid: (TOKS/BM, GN); block 256 = 4 waves; wave tr owns cols [tr*80, tr*80+80)
// Split-precision: logits = xh*wh + (xh*wl' + xl'*wh)/512, sigma ~ 2e-7.
__global__ __launch_bounds__(NTHR, 2) void k_mfma(
    const float* __restrict__ x, const int* __restrict__ mask,
    const float* __restrict__ gnoise, const float* __restrict__ bias,
    const float* __restrict__ cv, const _Float16* __restrict__ wh,
    const _Float16* __restrict__ wl, float* __restrict__ out,
    float* __restrict__ pp)
{
  __shared__ __align__(16) char smem[46464];
  float* lg   = (float*)smem;             // [32][LSTR] f32 logits
  float* psum = (float*)(smem + 41216);   // [4][CN]

  const int m0  = blockIdx.x * BM;
  const int g   = blockIdx.y;
  const int tid = threadIdx.x;
  const int tc  = tid & 63;        // lane
  const int tr  = tid >> 6;        // wave id = col-slice
  const int l15 = tid & 15;
  const int l4  = (tid & 63) >> 4; // k-group 0..3

  fx4 aH[2][5], aL[2][5];
  #pragma unroll
  for (int rf = 0; rf < 2; ++rf)
    #pragma unroll
    for (int cf = 0; cf < 5; ++cf) {
      aH[rf][cf] = (fx4){0.f, 0.f, 0.f, 0.f};
      aL[rf][cf] = (fx4){0.f, 0.f, 0.f, 0.f};
    }

  // A-frag (f32 x, converted in-reg): lane reads x[m0+rf*16+l15][l4*8 + k0*32 ..+8]
  const float* px0 = x + (size_t)(m0 + l15) * HD + l4 * 8;
  const float* px1 = px0 + (size_t)16 * HD;
  // B-frag: lane reads w[g*CN + tr*80 + cf*16 + l15][l4*8 + k0*32 ..+8]
  const size_t woff = (size_t)(g * CN + tr * 80 + l15) * HD + l4 * 8;
  const _Float16* pbh = wh + woff;
  const _Float16* pbl = wl + woff;

  #pragma unroll 4
  for (int k0 = 0; k0 < HD / 32; ++k0) {
    f16x8 ah[2], al[2];
    #pragma unroll
    for (int rf = 0; rf < 2; ++rf) {
      const float* p = (rf ? px1 : px0) + k0 * 32;
      fx4 u = *(const fx4*)p;
      fx4 v = *(const fx4*)(p + 4);
      #pragma unroll
      for (int e = 0; e < 4; ++e) {
        _Float16 hu = (_Float16)u[e], hv = (_Float16)v[e];
        ah[rf][e]     = hu;
        ah[rf][e + 4] = hv;
        al[rf][e]     = (_Float16)((u[e] - (float)hu) * 512.f);
        al[rf][e + 4] = (_Float16)((v[e] - (float)hv) * 512.f);
      }
    }
    #pragma unroll
    for (int cf = 0; cf < 5; ++cf) {
      f16x8 bh = *(const f16x8*)(pbh + (size_t)cf * 16 * HD + k0 * 32);
      f16x8 bl = *(const f16x8*)(pbl + (size_t)cf * 16 * HD + k0 * 32);
      #pragma unroll
      for (int rf = 0; rf < 2; ++rf) {
        aH[rf][cf] = __builtin_amdgcn_mfma_f32_16x16x32_f16(ah[rf], bh, aH[rf][cf], 0, 0, 0);
        aL[rf][cf] = __builtin_amdgcn_mfma_f32_16x16x32_f16(ah[rf], bl, aL[rf][cf], 0, 0, 0);
        aL[rf][cf] = __builtin_amdgcn_mfma_f32_16x16x32_f16(al[rf], bh, aL[rf][cf], 0, 0, 0);
      }
    }
  }

  // combine + bias, write logits to LDS.
  // C/D layout (m89-verified): col = lane&15, row = (lane>>4)*4 + e
  #pragma unroll
  for (int cf = 0; cf < 5; ++cf) {
    const int col = tr * 80 + cf * 16 + l15;
    const float bc = bias[g * CN + col];
    #pragma unroll
    for (int rf = 0; rf < 2; ++rf)
      #pragma unroll
      for (int e = 0; e < 4; ++e)
        lg[(rf * 16 + l4 * 4 + e) * LSTR + col] =
            aH[rf][cf][e] + aL[rf][cf][e] * (1.f / 512.f) + bc;
  }
  __syncthreads();

  // ---- verified epilogue (round 3), lg stride LSTR ----
  float pacc[5] = {0.f, 0.f, 0.f, 0.f, 0.f};
  #pragma unroll
  for (int i = 0; i < 8; ++i) {
    const int r = tr * 8 + i;
    const int n = m0 + r;
    const size_t grow = ((size_t)n * GN + g) * CN;
    float lv[5], gv[5];
    #pragma unroll
    for (int j = 0; j < 5; ++j) lv[j] = lg[r * LSTR + tc + 64 * j];
    #pragma unroll
    for (int j = 0; j < 5; ++j) gv[j] = gnoise[grow + tc + 64 * j];

    float bv = -3.4e38f; int bi = 1 << 30;
    #pragma unroll
    for (int j = 0; j < 5; ++j) {
      float v = lv[j] + gv[j];
      if (v > bv) { bv = v; bi = tc + 64 * j; }
    }
    for (int off = 1; off < 64; off <<= 1) {
      float ov = __shfl_xor(bv, off);
      int   oi = __shfl_xor(bi, off);
      if (ov > bv || (ov == bv && oi < bi)) { bv = ov; bi = oi; }
    }

    float mx = lv[0];
    #pragma unroll
    for (int j = 1; j < 5; ++j) mx = fmaxf(mx, lv[j]);
    for (int off = 1; off < 64; off <<= 1) mx = fmaxf(mx, __shfl_xor(mx, off));
    float e[5], s = 0.f;
    #pragma unroll
    for (int j = 0; j < 5; ++j) { e[j] = expf(lv[j] - mx); s += e[j]; }
    for (int off = 1; off < 64; off <<= 1) s += __shfl_xor(s, off);
    const float inv = 1.f / s;
    const float mlt = (mask[n] != 0) ? 1.f : 0.f;
    #pragma unroll
    for (int j = 0; j < 5; ++j) pacc[j] += mlt * e[j] * inv;

    const float2* cvr = (const float2*)(cv + ((size_t)(g * CN + bi)) * DN);
    float2* o2 = (float2*)(out + (size_t)n * (GN * DN) + g * DN);
    o2[tc] = cvr[tc];
  }

  #pragma unroll
  for (int j = 0; j < 5; ++j) psum[tr * CN + tc + 64 * j] = pacc[j];
  __syncthreads();
  for (int c = tid; c < CN; c += NTHR) {
    float s = psum[c] + psum[CN + c] + psum[2 * CN + c] + psum[3 * CN + c];
    atomicAdd(&pp[g * CN + c], s);
  }
}

// ---------------- fallback fp32 kernel (round-3 verified) ----------------
__global__ __launch_bounds__(NTHR) void k_main_fp32(
    const float* __restrict__ x, const int* __restrict__ mask,
    const float* __restrict__ gnoise, const float* __restrict__ W,
    const float* __restrict__ bias, const float* __restrict__ cv,
    float* __restrict__ out, float* __restrict__ pp)
{
  __shared__ __align__(16) char smem[47360];
  float* w_lds = (float*)smem;
  float* xs    = (float*)(smem + 42240);
  float* lg    = (float*)smem;
  float* psum  = (float*)(smem + 42240);

  const int m0  = blockIdx.x * BM;
  const int g   = blockIdx.y;
  const int tid = threadIdx.x;
  const int tc  = tid & 63;
  const int tr  = tid >> 6;
  const int r0  = tr * 8;

  float acc[8][5];
  #pragma unroll
  for (int i = 0; i < 8; ++i)
    #pragma unroll
    for (int j = 0; j < 5; ++j) acc[i][j] = 0.f;

  const float* Wg = W + (size_t)g * CN * HD;

  for (int k0 = 0; k0 < HD; k0 += 32) {
    __syncthreads();
    #pragma unroll
    for (int t = 0; t < 10; ++t) {
      int idx = tid + t * NTHR;
      int c   = idx >> 3;
      int k4  = idx & 7;
      float4 wv4 = *(const float4*)(Wg + (size_t)c * HD + k0 + k4 * 4);
      float* dst = &w_lds[c * WSTR + k4 * 4];
      dst[0] = wv4.x; dst[1] = wv4.y; dst[2] = wv4.z; dst[3] = wv4.w;
    }
    {
      int r = tid >> 3, k4 = tid & 7;
      float4 xv = *(const float4*)(x + (size_t)(m0 + r) * HD + k0 + k4 * 4);
      float* dst = &xs[r * 32 + k4 * 4];
      dst[0] = xv.x; dst[1] = xv.y; dst[2] = xv.z; dst[3] = xv.w;
    }
    __syncthreads();
    #pragma unroll
    for (int kk = 0; kk < 32; kk += 4) {
      float xq[8][4];
      #pragma unroll
      for (int i = 0; i < 8; ++i) {
        float4 t4 = *(const float4*)&xs[(r0 + i) * 32 + kk];
        xq[i][0] = t4.x; xq[i][1] = t4.y; xq[i][2] = t4.z; xq[i][3] = t4.w;
      }
      #pragma unroll
      for (int q = 0; q < 4; ++q) {
        float wv[5];
        #pragma unroll
        for (int j = 0; j < 5; ++j) wv[j] = w_lds[(tc + 64 * j) * WSTR + kk + q];
        #pragma unroll
        for (int i = 0; i < 8; ++i)
          #pragma unroll
          for (int j = 0; j < 5; ++j)
            acc[i][j] = fmaf(xq[i][q], wv[j], acc[i][j]);
      }
    }
  }
  __syncthreads();

  float bj[5];
  #pragma unroll
  for (int j = 0; j < 5; ++j) bj[j] = bias[g * CN + tc + 64 * j];
  #pragma unroll
  for (int i = 0; i < 8; ++i)
    #pragma unroll
    for (int j = 0; j < 5; ++j)
      lg[(r0 + i) * CN + tc + 64 * j] = acc[i][j] + bj[j];
  __syncthreads();

  float pacc[5] = {0.f, 0.f, 0.f, 0.f, 0.f};
  #pragma unroll
  for (int i = 0; i < 8; ++i) {
    const int r = r0 + i;
    const int n = m0 + r;
    const size_t grow = ((size_t)n * GN + g) * CN;
    float lv[5], gv[5];
    #pragma unroll
    for (int j = 0; j < 5; ++j) lv[j] = lg[r * CN + tc + 64 * j];
    #pragma unroll
    for (int j = 0; j < 5; ++j) gv[j] = gnoise[grow + tc + 64 * j];

    float bv = -3.4e38f; int bi = 1 << 30;
    #pragma unroll
    for (int j = 0; j < 5; ++j) {
      float v = lv[j] + gv[j];
      if (v > bv) { bv = v; bi = tc + 64 * j; }
    }
    for (int off = 1; off < 64; off <<= 1) {
      float ov = __shfl_xor(bv, off);
      int   oi = __shfl_xor(bi, off);
      if (ov > bv || (ov == bv && oi < bi)) { bv = ov; bi = oi; }
    }

    float mx = lv[0];
    #pragma unroll
    for (int j = 1; j < 5; ++j) mx = fmaxf(mx, lv[j]);
    for (int off = 1; off < 64; off <<= 1) mx = fmaxf(mx, __shfl_xor(mx, off));
    float e[5], s = 0.f;
    #pragma unroll
    for (int j = 0; j < 5; ++j) { e[j] = expf(lv[j] - mx); s += e[j]; }
    for (int off = 1; off < 64; off <<= 1) s += __shfl_xor(s, off);
    const float inv = 1.f / s;
    const float mlt = (mask[n] != 0) ? 1.f : 0.f;
    #pragma unroll
    for (int j = 0; j < 5; ++j) pacc[j] += mlt * e[j] * inv;

    const float2* cvr = (const float2*)(cv + ((size_t)(g * CN + bi)) * DN);
    float2* o2 = (float2*)(out + (size_t)n * (GN * DN) + g * DN);
    o2[tc] = cvr[tc];
  }

  #pragma unroll
  for (int j = 0; j < 5; ++j) psum[tr * CN + tc + 64 * j] = pacc[j];
  __syncthreads();
  for (int c = tid; c < CN; c += NTHR) {
    float s = psum[c] + psum[CN + c] + psum[2 * CN + c] + psum[3 * CN + c];
    atomicAdd(&pp[g * CN + c], s);
  }
}

// ---------------- perplexity finalize ----------------
__global__ __launch_bounds__(640) void k_final(
    const float* __restrict__ pp, const int* __restrict__ mask,
    float* __restrict__ out, int out_off)
{
  __shared__ float red[10];
  __shared__ float eL[GN * CN];
  __shared__ float perp_parts[GN];
  const int tid = threadIdx.x;

  float cnt = 0.f;
  for (int i = tid; i < TOKS; i += 640) cnt += (mask[i] != 0) ? 1.f : 0.f;
  for (int off = 1; off < 64; off <<= 1) cnt += __shfl_xor(cnt, off);
  if ((tid & 63) == 0) red[tid >> 6] = cnt;
  __syncthreads();
  float denom = 0.f;
  #pragma unroll
  for (int w = 0; w < 10; ++w) denom += red[w];
  denom = fmaxf(denom, 1.f);

  const float p = pp[tid] / denom;
  eL[tid] = p * logf(p + 1e-7f);
  __syncthreads();

  if (tid < 2 * 64) {
    const int gg = tid >> 6, ll = tid & 63;
    float s = 0.f;
    #pragma unroll
    for (int j = 0; j < 5; ++j) s += eL[gg * CN + ll + 64 * j];
    for (int off = 1; off < 64; off <<= 1) s += __shfl_xor(s, off);
    if (ll == 0) perp_parts[gg] = expf(-s);
  }
  __syncthreads();
  if (tid == 0) out[out_off] = perp_parts[0] + perp_parts[1];
}

extern "C" void kernel_launch(void* const* d_in, const int* in_sizes, int n_in,
                              void* d_out, int out_size, void* d_ws, size_t ws_size,
                              hipStream_t stream) {
  const float* x     = (const float*)d_in[0];
  const int*   mask  = (const int*)d_in[1];
  const float* gn    = (const float*)d_in[2];
  const float* W     = (const float*)d_in[3];
  const float* bias  = (const float*)d_in[4];
  const float* cv    = (const float*)d_in[5];
  float* out = (float*)d_out;
  float* pp  = (float*)d_ws;

  hipLaunchKernelGGL(k_zero, dim3(1), dim3(640), 0, stream, pp);

  if (ws_size >= WS_NEED) {
    _Float16* wh = (_Float16*)((char*)d_ws + WS_W_OFF);
    _Float16* wl = wh + (size_t)(GN * CN) * HD;
    hipLaunchKernelGGL(k_wsplit, dim3(GN * CN * HD / 1024), dim3(256), 0, stream,
                       W, wh, wl);
    hipLaunchKernelGGL(k_mfma, dim3(TOKS / BM, GN), dim3(NTHR), 0, stream,
                       x, mask, gn, bias, cv, wh, wl, out, pp);
  } else {
    hipLaunchKernelGGL(k_main_fp32, dim3(TOKS / BM, GN), dim3(NTHR), 0, stream,
                       x, mask, gn, W, bias, cv, out, pp);
  }

  hipLaunchKernelGGL(k_final, dim3(1), dim3(640), 0, stream,
                     pp, mask, out, out_size - 1);
}

// Round 5
// 314.961 us; speedup vs baseline: 3.6106x; 1.3420x over previous
//
#include <hip/hip_runtime.h>
#include <hip/hip_bf16.h>
#include <math.h>

#define TOKS 49152   // B*T
#define HD   512     // hidden
#define GN   2       // groups
#define CN   320     // codes per group
#define DN   128     // code dim
#define BM   32      // tokens per block
#define NTHR 256
#define LSTR 321     // lg row stride (f32): epilogue reads 2-way (free)
#define WSTR 33      // fp32-fallback W LDS stride

#define WS_WELEMS ((size_t)(GN * CN) * HD)   // 327680
#define WS_XELEMS ((size_t)TOKS * HD)        // 25165824
#define WS_W_OFF  4096
#define WS_X_OFF  (WS_W_OFF + 4 * WS_WELEMS)            // wh+wl, 2B each
#define WS_MID    WS_X_OFF                               // ~1.3 MB
#define WS_BIG    (WS_X_OFF + 4 * WS_XELEMS)             // ~102 MB

typedef _Float16 f16x8 __attribute__((ext_vector_type(8)));
typedef float    fx4   __attribute__((ext_vector_type(4)));

// ---------------- zero the p-accumulator ----------------
__global__ void k_zero(float* pp) {
  int t = threadIdx.x;
  if (t < GN * CN) pp[t] = 0.f;
}

// -------- fragment-major (hi, lo*512) f16 splitter --------
// Output elem t*8..t*8+8 is FRAG order: blob b = t>>6 holds a 16-row x 32-k
// tile; lane l = t&63 holds row rb*16+(l&15), k = k0*32+(l>>4)*8, 8 elems.
// Writes are perfectly linear; reads are 32B/row gathers (one-shot pass).
__global__ __launch_bounds__(256) void k_split(const float* __restrict__ src,
                                               _Float16* __restrict__ dh,
                                               _Float16* __restrict__ dl) {
  size_t t    = (size_t)blockIdx.x * 256 + threadIdx.x;
  int    lane = (int)(t & 63);
  size_t blob = t >> 6;
  int    k0   = (int)(blob & 15);
  size_t rb   = blob >> 4;
  const float* p = src + (rb * 16 + (lane & 15)) * HD + k0 * 32 + (lane >> 4) * 8;
  fx4 u = *(const fx4*)p;
  fx4 v = *(const fx4*)(p + 4);
  f16x8 h8, l8;
  #pragma unroll
  for (int e = 0; e < 4; ++e) {
    _Float16 hu = (_Float16)u[e], hv = (_Float16)v[e];
    h8[e]     = hu;
    h8[e + 4] = hv;
    l8[e]     = (_Float16)((u[e] - (float)hu) * 512.f);   // exact residual, pow2 scale
    l8[e + 4] = (_Float16)((v[e] - (float)hv) * 512.f);
  }
  *(f16x8*)(dh + t * 8) = h8;
  *(f16x8*)(dl + t * 8) = l8;
}

// ---------------- fused MFMA GEMM + epilogue ----------------
// grid (TOKS/BM, GN), 4 waves; wave tr owns cols [tr*80, tr*80+80).
// XS=true: A from frag-major xh/xl (zero VALU cvt in loop).
// XS=false: A from f32 x with in-register split (mid-ws path).
template <bool XS>
__global__ __launch_bounds__(NTHR, 2) void k_mfma_frag(
    const float* __restrict__ x, const _Float16* __restrict__ xh,
    const _Float16* __restrict__ xl, const int* __restrict__ mask,
    const float* __restrict__ gnoise, const float* __restrict__ bias,
    const float* __restrict__ cv, const _Float16* __restrict__ wh,
    const _Float16* __restrict__ wl, float* __restrict__ out,
    float* __restrict__ pp)
{
  __shared__ __align__(16) char smem[46464];
  float* lg   = (float*)smem;             // [32][LSTR]
  float* psum = (float*)(smem + 41216);   // [4][CN]

  const int m0  = blockIdx.x * BM;
  const int mb0 = blockIdx.x * 2;         // 16-row blocks
  const int g   = blockIdx.y;
  const int tid = threadIdx.x;
  const int tc  = tid & 63;
  const int tr  = tid >> 6;
  const int l15 = tid & 15;
  const int l4  = (tid & 63) >> 4;

  fx4 aH[2][5], aL[2][5];
  #pragma unroll
  for (int rf = 0; rf < 2; ++rf)
    #pragma unroll
    for (int cf = 0; cf < 5; ++cf) {
      aH[rf][cf] = (fx4){0.f, 0.f, 0.f, 0.f};
      aL[rf][cf] = (fx4){0.f, 0.f, 0.f, 0.f};
    }

  // frag-major bases: blob (rb*16+k0) -> elems blob*512 + lane*8; k-step = 512 elems.
  const size_t ln8 = (size_t)tc * 8;
  const _Float16* pxh0 = xh + (size_t)(mb0 + 0) * 16 * 512 + ln8;
  const _Float16* pxl0 = xl + (size_t)(mb0 + 0) * 16 * 512 + ln8;
  const _Float16* pxh1 = xh + (size_t)(mb0 + 1) * 16 * 512 + ln8;
  const _Float16* pxl1 = xl + (size_t)(mb0 + 1) * 16 * 512 + ln8;
  const float* px0 = x + (size_t)(m0 + l15) * HD + l4 * 8;   // XS=false path
  const float* px1 = px0 + (size_t)16 * HD;
  const _Float16* pbh[5];
  const _Float16* pbl[5];
  #pragma unroll
  for (int cf = 0; cf < 5; ++cf) {
    const size_t cb = (size_t)(g * 20 + tr * 5 + cf) * 16 * 512 + ln8;
    pbh[cf] = wh + cb;
    pbl[cf] = wl + cb;
  }

  // named double-buffer frags (rule #20: no runtime-indexed buffers)
  f16x8 A0h_a, A0l_a, A1h_a, A1l_a, Bh_a[5], Bl_a[5];
  f16x8 A0h_b, A0l_b, A1h_b, A1l_b, Bh_b[5], Bl_b[5];

#define LOADK(SUF, K) do {                                                   \
    if constexpr (XS) {                                                      \
      A0h_##SUF = *(const f16x8*)(pxh0 + (size_t)(K) * 512);                 \
      A0l_##SUF = *(const f16x8*)(pxl0 + (size_t)(K) * 512);                 \
      A1h_##SUF = *(const f16x8*)(pxh1 + (size_t)(K) * 512);                 \
      A1l_##SUF = *(const f16x8*)(pxl1 + (size_t)(K) * 512);                 \
    } else {                                                                 \
      const float* _p0 = px0 + (K) * 32;                                     \
      const float* _p1 = px1 + (K) * 32;                                     \
      fx4 _u0 = *(const fx4*)_p0, _v0 = *(const fx4*)(_p0 + 4);              \
      fx4 _u1 = *(const fx4*)_p1, _v1 = *(const fx4*)(_p1 + 4);              \
      _Pragma("unroll")                                                      \
      for (int e = 0; e < 4; ++e) {                                          \
        _Float16 h;                                                          \
        h = (_Float16)_u0[e]; A0h_##SUF[e]   = h;                            \
        A0l_##SUF[e]   = (_Float16)((_u0[e] - (float)h) * 512.f);            \
        h = (_Float16)_v0[e]; A0h_##SUF[e+4] = h;                            \
        A0l_##SUF[e+4] = (_Float16)((_v0[e] - (float)h) * 512.f);            \
        h = (_Float16)_u1[e]; A1h_##SUF[e]   = h;                            \
        A1l_##SUF[e]   = (_Float16)((_u1[e] - (float)h) * 512.f);            \
        h = (_Float16)_v1[e]; A1h_##SUF[e+4] = h;                            \
        A1l_##SUF[e+4] = (_Float16)((_v1[e] - (float)h) * 512.f);            \
      }                                                                      \
    }                                                                        \
    _Pragma("unroll")                                                        \
    for (int cf = 0; cf < 5; ++cf) {                                         \
      Bh_##SUF[cf] = *(const f16x8*)(pbh[cf] + (size_t)(K) * 512);           \
      Bl_##SUF[cf] = *(const f16x8*)(pbl[cf] + (size_t)(K) * 512);           \
    }                                                                        \
  } while (0)

#define MFMAK(SUF) do {                                                      \
    _Pragma("unroll")                                                        \
    for (int cf = 0; cf < 5; ++cf) {                                         \
      aH[0][cf] = __builtin_amdgcn_mfma_f32_16x16x32_f16(A0h_##SUF, Bh_##SUF[cf], aH[0][cf], 0, 0, 0); \
      aH[1][cf] = __builtin_amdgcn_mfma_f32_16x16x32_f16(A1h_##SUF, Bh_##SUF[cf], aH[1][cf], 0, 0, 0); \
      aL[0][cf] = __builtin_amdgcn_mfma_f32_16x16x32_f16(A0h_##SUF, Bl_##SUF[cf], aL[0][cf], 0, 0, 0); \
      aL[0][cf] = __builtin_amdgcn_mfma_f32_16x16x32_f16(A0l_##SUF, Bh_##SUF[cf], aL[0][cf], 0, 0, 0); \
      aL[1][cf] = __builtin_amdgcn_mfma_f32_16x16x32_f16(A1h_##SUF, Bl_##SUF[cf], aL[1][cf], 0, 0, 0); \
      aL[1][cf] = __builtin_amdgcn_mfma_f32_16x16x32_f16(A1l_##SUF, Bh_##SUF[cf], aL[1][cf], 0, 0, 0); \
    }                                                                        \
  } while (0)

  LOADK(a, 0);
  #pragma unroll
  for (int k0 = 0; k0 < 16; k0 += 2) {
    if (k0 + 1 < 16) LOADK(b, k0 + 1);
    MFMAK(a);
    if (k0 + 2 < 16) LOADK(a, k0 + 2);
    MFMAK(b);
  }
#undef LOADK
#undef MFMAK

  // combine + bias -> lg. C/D: col = l15, row = l4*4 + e (HW-verified r4).
  #pragma unroll
  for (int cf = 0; cf < 5; ++cf) {
    const int col = tr * 80 + cf * 16 + l15;
    const float bc = bias[g * CN + col];
    #pragma unroll
    for (int rf = 0; rf < 2; ++rf)
      #pragma unroll
      for (int e = 0; e < 4; ++e)
        lg[(rf * 16 + l4 * 4 + e) * LSTR + col] =
            aH[rf][cf][e] + aL[rf][cf][e] * (1.f / 512.f) + bc;
  }
  __syncthreads();

  // ---- verified epilogue ----
  float pacc[5] = {0.f, 0.f, 0.f, 0.f, 0.f};
  #pragma unroll
  for (int i = 0; i < 8; ++i) {
    const int r = tr * 8 + i;
    const int n = m0 + r;
    const size_t grow = ((size_t)n * GN + g) * CN;
    float lv[5], gv[5];
    #pragma unroll
    for (int j = 0; j < 5; ++j) lv[j] = lg[r * LSTR + tc + 64 * j];
    #pragma unroll
    for (int j = 0; j < 5; ++j) gv[j] = gnoise[grow + tc + 64 * j];

    float bv = -3.4e38f; int bi = 1 << 30;
    #pragma unroll
    for (int j = 0; j < 5; ++j) {
      float v = lv[j] + gv[j];
      if (v > bv) { bv = v; bi = tc + 64 * j; }
    }
    for (int off = 1; off < 64; off <<= 1) {
      float ov = __shfl_xor(bv, off);
      int   oi = __shfl_xor(bi, off);
      if (ov > bv || (ov == bv && oi < bi)) { bv = ov; bi = oi; }
    }

    float mx = lv[0];
    #pragma unroll
    for (int j = 1; j < 5; ++j) mx = fmaxf(mx, lv[j]);
    for (int off = 1; off < 64; off <<= 1) mx = fmaxf(mx, __shfl_xor(mx, off));
    float e[5], s = 0.f;
    #pragma unroll
    for (int j = 0; j < 5; ++j) { e[j] = expf(lv[j] - mx); s += e[j]; }
    for (int off = 1; off < 64; off <<= 1) s += __shfl_xor(s, off);
    const float inv = 1.f / s;
    const float mlt = (mask[n] != 0) ? 1.f : 0.f;
    #pragma unroll
    for (int j = 0; j < 5; ++j) pacc[j] += mlt * e[j] * inv;

    const float2* cvr = (const float2*)(cv + ((size_t)(g * CN + bi)) * DN);
    float2* o2 = (float2*)(out + (size_t)n * (GN * DN) + g * DN);
    o2[tc] = cvr[tc];
  }

  #pragma unroll
  for (int j = 0; j < 5; ++j) psum[tr * CN + tc + 64 * j] = pacc[j];
  __syncthreads();
  for (int c = tid; c < CN; c += NTHR) {
    float s = psum[c] + psum[CN + c] + psum[2 * CN + c] + psum[3 * CN + c];
    atomicAdd(&pp[g * CN + c], s);
  }
}

// ---------------- fp32 fallback (round-3 verified) ----------------
__global__ __launch_bounds__(NTHR) void k_main_fp32(
    const float* __restrict__ x, const int* __restrict__ mask,
    const float* __restrict__ gnoise, const float* __restrict__ W,
    const float* __restrict__ bias, const float* __restrict__ cv,
    float* __restrict__ out, float* __restrict__ pp)
{
  __shared__ __align__(16) char smem[47360];
  float* w_lds = (float*)smem;
  float* xs    = (float*)(smem + 42240);
  float* lg    = (float*)smem;
  float* psum  = (float*)(smem + 42240);

  const int m0  = blockIdx.x * BM;
  const int g   = blockIdx.y;
  const int tid = threadIdx.x;
  const int tc  = tid & 63;
  const int tr  = tid >> 6;
  const int r0  = tr * 8;

  float acc[8][5];
  #pragma unroll
  for (int i = 0; i < 8; ++i)
    #pragma unroll
    for (int j = 0; j < 5; ++j) acc[i][j] = 0.f;

  const float* Wg = W + (size_t)g * CN * HD;

  for (int k0 = 0; k0 < HD; k0 += 32) {
    __syncthreads();
    #pragma unroll
    for (int t = 0; t < 10; ++t) {
      int idx = tid + t * NTHR;
      int c   = idx >> 3;
      int k4  = idx & 7;
      float4 wv4 = *(const float4*)(Wg + (size_t)c * HD + k0 + k4 * 4);
      float* dst = &w_lds[c * WSTR + k4 * 4];
      dst[0] = wv4.x; dst[1] = wv4.y; dst[2] = wv4.z; dst[3] = wv4.w;
    }
    {
      int r = tid >> 3, k4 = tid & 7;
      float4 xv = *(const float4*)(x + (size_t)(m0 + r) * HD + k0 + k4 * 4);
      float* dst = &xs[r * 32 + k4 * 4];
      dst[0] = xv.x; dst[1] = xv.y; dst[2] = xv.z; dst[3] = xv.w;
    }
    __syncthreads();
    #pragma unroll
    for (int kk = 0; kk < 32; kk += 4) {
      float xq[8][4];
      #pragma unroll
      for (int i = 0; i < 8; ++i) {
        float4 t4 = *(const float4*)&xs[(r0 + i) * 32 + kk];
        xq[i][0] = t4.x; xq[i][1] = t4.y; xq[i][2] = t4.z; xq[i][3] = t4.w;
      }
      #pragma unroll
      for (int q = 0; q < 4; ++q) {
        float wv[5];
        #pragma unroll
        for (int j = 0; j < 5; ++j) wv[j] = w_lds[(tc + 64 * j) * WSTR + kk + q];
        #pragma unroll
        for (int i = 0; i < 8; ++i)
          #pragma unroll
          for (int j = 0; j < 5; ++j)
            acc[i][j] = fmaf(xq[i][q], wv[j], acc[i][j]);
      }
    }
  }
  __syncthreads();

  float bj[5];
  #pragma unroll
  for (int j = 0; j < 5; ++j) bj[j] = bias[g * CN + tc + 64 * j];
  #pragma unroll
  for (int i = 0; i < 8; ++i)
    #pragma unroll
    for (int j = 0; j < 5; ++j)
      lg[(r0 + i) * CN + tc + 64 * j] = acc[i][j] + bj[j];
  __syncthreads();

  float pacc[5] = {0.f, 0.f, 0.f, 0.f, 0.f};
  #pragma unroll
  for (int i = 0; i < 8; ++i) {
    const int r = r0 + i;
    const int n = m0 + r;
    const size_t grow = ((size_t)n * GN + g) * CN;
    float lv[5], gv[5];
    #pragma unroll
    for (int j = 0; j < 5; ++j) lv[j] = lg[r * CN + tc + 64 * j];
    #pragma unroll
    for (int j = 0; j < 5; ++j) gv[j] = gnoise[grow + tc + 64 * j];

    float bv = -3.4e38f; int bi = 1 << 30;
    #pragma unroll
    for (int j = 0; j < 5; ++j) {
      float v = lv[j] + gv[j];
      if (v > bv) { bv = v; bi = tc + 64 * j; }
    }
    for (int off = 1; off < 64; off <<= 1) {
      float ov = __shfl_xor(bv, off);
      int   oi = __shfl_xor(bi, off);
      if (ov > bv || (ov == bv && oi < bi)) { bv = ov; bi = oi; }
    }

    float mx = lv[0];
    #pragma unroll
    for (int j = 1; j < 5; ++j) mx = fmaxf(mx, lv[j]);
    for (int off = 1; off < 64; off <<= 1) mx = fmaxf(mx, __shfl_xor(mx, off));
    float e[5], s = 0.f;
    #pragma unroll
    for (int j = 0; j < 5; ++j) { e[j] = expf(lv[j] - mx); s += e[j]; }
    for (int off = 1; off < 64; off <<= 1) s += __shfl_xor(s, off);
    const float inv = 1.f / s;
    const float mlt = (mask[n] != 0) ? 1.f : 0.f;
    #pragma unroll
    for (int j = 0; j < 5; ++j) pacc[j] += mlt * e[j] * inv;

    const float2* cvr = (const float2*)(cv + ((size_t)(g * CN + bi)) * DN);
    float2* o2 = (float2*)(out + (size_t)n * (GN * DN) + g * DN);
    o2[tc] = cvr[tc];
  }

  #pragma unroll
  for (int j = 0; j < 5; ++j) psum[tr * CN + tc + 64 * j] = pacc[j];
  __syncthreads();
  for (int c = tid; c < CN; c += NTHR) {
    float s = psum[c] + psum[CN + c] + psum[2 * CN + c] + psum[3 * CN + c];
    atomicAdd(&pp[g * CN + c], s);
  }
}

// ---------------- perplexity finalize ----------------
__global__ __launch_bounds__(640) void k_final(
    const float* __restrict__ pp, const int* __restrict__ mask,
    float* __restrict__ out, int out_off)
{
  __shared__ float red[10];
  __shared__ float eL[GN * CN];
  __shared__ float perp_parts[GN];
  const int tid = threadIdx.x;

  float cnt = 0.f;
  for (int i = tid; i < TOKS; i += 640) cnt += (mask[i] != 0) ? 1.f : 0.f;
  for (int off = 1; off < 64; off <<= 1) cnt += __shfl_xor(cnt, off);
  if ((tid & 63) == 0) red[tid >> 6] = cnt;
  __syncthreads();
  float denom = 0.f;
  #pragma unroll
  for (int w = 0; w < 10; ++w) denom += red[w];
  denom = fmaxf(denom, 1.f);

  const float p = pp[tid] / denom;
  eL[tid] = p * logf(p + 1e-7f);
  __syncthreads();

  if (tid < 2 * 64) {
    const int gg = tid >> 6, ll = tid & 63;
    float s = 0.f;
    #pragma unroll
    for (int j = 0; j < 5; ++j) s += eL[gg * CN + ll + 64 * j];
    for (int off = 1; off < 64; off <<= 1) s += __shfl_xor(s, off);
    if (ll == 0) perp_parts[gg] = expf(-s);
  }
  __syncthreads();
  if (tid == 0) out[out_off] = perp_parts[0] + perp_parts[1];
}

extern "C" void kernel_launch(void* const* d_in, const int* in_sizes, int n_in,
                              void* d_out, int out_size, void* d_ws, size_t ws_size,
                              hipStream_t stream) {
  const float* x     = (const float*)d_in[0];
  const int*   mask  = (const int*)d_in[1];
  const float* gn    = (const float*)d_in[2];
  const float* W     = (const float*)d_in[3];
  const float* bias  = (const float*)d_in[4];
  const float* cv    = (const float*)d_in[5];
  float* out = (float*)d_out;
  float* pp  = (float*)d_ws;

  hipLaunchKernelGGL(k_zero, dim3(1), dim3(640), 0, stream, pp);

  if (ws_size >= WS_MID) {
    _Float16* wh = (_Float16*)((char*)d_ws + WS_W_OFF);
    _Float16* wl = wh + WS_WELEMS;
    hipLaunchKernelGGL(k_split, dim3((int)(WS_WELEMS / 8 / 256)), dim3(256), 0,
                       stream, W, wh, wl);
    if (ws_size >= WS_BIG) {
      _Float16* xh = (_Float16*)((char*)d_ws + WS_X_OFF);
      _Float16* xl = xh + WS_XELEMS;
      hipLaunchKernelGGL(k_split, dim3((int)(WS_XELEMS / 8 / 256)), dim3(256), 0,
                         stream, x, xh, xl);
      k_mfma_frag<true><<<dim3(TOKS / BM, GN), dim3(NTHR), 0, stream>>>(
          x, xh, xl, mask, gn, bias, cv, wh, wl, out, pp);
    } else {
      k_mfma_frag<false><<<dim3(TOKS / BM, GN), dim3(NTHR), 0, stream>>>(
          x, (const _Float16*)nullptr, (const _Float16*)nullptr, mask, gn, bias,
          cv, wh, wl, out, pp);
    }
  } else {
    hipLaunchKernelGGL(k_main_fp32, dim3(TOKS / BM, GN), dim3(NTHR), 0, stream,
                       x, mask, gn, W, bias, cv, out, pp);
  }

  hipLaunchKernelGGL(k_final, dim3(1), dim3(640), 0, stream,
                     pp, mask, out, out_size - 1);
}

// Round 6
// 242.206 us; speedup vs baseline: 4.6952x; 1.3004x over previous
//
#include <hip/hip_runtime.h>
#include <hip/hip_bf16.h>
#include <math.h>

#define TOKS 49152   // B*T
#define HD   512     // hidden
#define GN   2       // groups
#define CN   320     // codes per group
#define DN   128     // code dim
#define BM   32      // tokens per block
#define NTHR 256
#define LSTR 321     // lg row stride (f32): epilogue reads 2-way (free)
#define WSTR 33      // fp32-fallback W LDS stride

#define WS_WELEMS ((size_t)(GN * CN) * HD)   // 327680
#define WS_W_OFF  4096
#define WS_MID    (WS_W_OFF + 4 * WS_WELEMS) // pp + wh + wl (~1.3 MB)

typedef _Float16 f16x8 __attribute__((ext_vector_type(8)));
typedef float    fx4   __attribute__((ext_vector_type(4)));

// ---------------- zero the p-accumulator ----------------
__global__ void k_zero(float* pp) {
  int t = threadIdx.x;
  if (t < GN * CN) pp[t] = 0.f;
}

// -------- W fragment-major (hi, lo*512) f16 splitter (r5-verified) ------
__global__ __launch_bounds__(256) void k_split(const float* __restrict__ src,
                                               _Float16* __restrict__ dh,
                                               _Float16* __restrict__ dl) {
  size_t t    = (size_t)blockIdx.x * 256 + threadIdx.x;
  int    lane = (int)(t & 63);
  size_t blob = t >> 6;
  int    k0   = (int)(blob & 15);
  size_t rb   = blob >> 4;
  const float* p = src + (rb * 16 + (lane & 15)) * HD + k0 * 32 + (lane >> 4) * 8;
  fx4 u = *(const fx4*)p;
  fx4 v = *(const fx4*)(p + 4);
  f16x8 h8, l8;
  #pragma unroll
  for (int e = 0; e < 4; ++e) {
    _Float16 hu = (_Float16)u[e], hv = (_Float16)v[e];
    h8[e]     = hu;
    h8[e + 4] = hv;
    l8[e]     = (_Float16)((u[e] - (float)hu) * 512.f);
    l8[e + 4] = (_Float16)((v[e] - (float)hv) * 512.f);
  }
  *(f16x8*)(dh + t * 8) = h8;
  *(f16x8*)(dl + t * 8) = l8;
}

// ---------------- fused MFMA GEMM + epilogue ----------------
// grid 3072; u -> mt=((u>>4)<<3)|(u&7), g=(u>>3)&1 so the two g-twins of an
// m-tile land on the SAME XCD (u%8 equal), 8 dispatches apart -> x L2 reuse.
__global__ __launch_bounds__(NTHR, 2) void k_gemm_ep(
    const float* __restrict__ x, const int* __restrict__ mask,
    const float* __restrict__ gnoise, const float* __restrict__ bias,
    const float* __restrict__ cv, const _Float16* __restrict__ wh,
    const _Float16* __restrict__ wl, float* __restrict__ out,
    float* __restrict__ pp)
{
  __shared__ __align__(16) char smem[46464];
  float* lg   = (float*)smem;             // [32][LSTR]
  float* psum = (float*)(smem + 41216);   // [4][CN]

  const int u   = blockIdx.x;
  const int mt  = ((u >> 4) << 3) | (u & 7);
  const int g   = (u >> 3) & 1;
  const int m0  = mt * BM;
  const int tid = threadIdx.x;
  const int tc  = tid & 63;
  const int tr  = __builtin_amdgcn_readfirstlane(tid >> 6);  // wave-uniform
  const int l15 = tid & 15;
  const int l4  = (tid & 63) >> 4;

  fx4 aH[2][5], aL[2][5];
  #pragma unroll
  for (int rf = 0; rf < 2; ++rf)
    #pragma unroll
    for (int cf = 0; cf < 5; ++cf) {
      aH[rf][cf] = (fx4){0.f, 0.f, 0.f, 0.f};
      aL[rf][cf] = (fx4){0.f, 0.f, 0.f, 0.f};
    }

  // A: f32 x, frag addressing (r4-verified): row m0+rf*16+l15, k = K*32+l4*8
  const float* pA0 = x + (size_t)(m0 + l15) * HD + l4 * 8;
  const float* pA1 = pA0 + (size_t)16 * HD;
  // B: frag-major wh/wl (r5-verified): blob rb = g*20+tr*5+cf, lane slot tc*8
  const _Float16* pBh[5];
  const _Float16* pBl[5];
  #pragma unroll
  for (int cf = 0; cf < 5; ++cf) {
    const size_t cb = (size_t)(g * 20 + tr * 5 + cf) * 8192 + (size_t)tc * 8;
    pBh[cf] = wh + cb;
    pBl[cf] = wl + cb;
  }

  // named double-buffer raw loads + shared current A-frags (rule #20: static)
  fx4 x0u_a, x0v_a, x1u_a, x1v_a, x0u_b, x0v_b, x1u_b, x1v_b;
  f16x8 Bh_a[5], Bl_a[5], Bh_b[5], Bl_b[5];
  f16x8 A0h, A0l, A1h, A1l;

#define LOADB(S, K) do {                                                     \
    x0u_##S = *(const fx4*)(pA0 + (size_t)(K) * 32);                         \
    x0v_##S = *(const fx4*)(pA0 + (size_t)(K) * 32 + 4);                     \
    x1u_##S = *(const fx4*)(pA1 + (size_t)(K) * 32);                         \
    x1v_##S = *(const fx4*)(pA1 + (size_t)(K) * 32 + 4);                     \
    _Pragma("unroll")                                                        \
    for (int cf = 0; cf < 5; ++cf) {                                         \
      Bh_##S[cf] = *(const f16x8*)(pBh[cf] + (size_t)(K) * 512);             \
      Bl_##S[cf] = *(const f16x8*)(pBl[cf] + (size_t)(K) * 512);             \
    }                                                                        \
  } while (0)

#define CVT(S) do {                                                          \
    _Pragma("unroll")                                                        \
    for (int e = 0; e < 4; ++e) {                                            \
      _Float16 h; float f;                                                   \
      f = x0u_##S[e]; h = (_Float16)f; A0h[e]   = h;                         \
      A0l[e]   = (_Float16)((f - (float)h) * 512.f);                         \
      f = x0v_##S[e]; h = (_Float16)f; A0h[e+4] = h;                         \
      A0l[e+4] = (_Float16)((f - (float)h) * 512.f);                         \
      f = x1u_##S[e]; h = (_Float16)f; A1h[e]   = h;                         \
      A1l[e]   = (_Float16)((f - (float)h) * 512.f);                         \
      f = x1v_##S[e]; h = (_Float16)f; A1h[e+4] = h;                         \
      A1l[e+4] = (_Float16)((f - (float)h) * 512.f);                         \
    }                                                                        \
  } while (0)

#define MFMAK(S) do {                                                        \
    _Pragma("unroll")                                                        \
    for (int cf = 0; cf < 5; ++cf) {                                         \
      aH[0][cf] = __builtin_amdgcn_mfma_f32_16x16x32_f16(A0h, Bh_##S[cf], aH[0][cf], 0, 0, 0); \
      aH[1][cf] = __builtin_amdgcn_mfma_f32_16x16x32_f16(A1h, Bh_##S[cf], aH[1][cf], 0, 0, 0); \
      aL[0][cf] = __builtin_amdgcn_mfma_f32_16x16x32_f16(A0h, Bl_##S[cf], aL[0][cf], 0, 0, 0); \
      aL[0][cf] = __builtin_amdgcn_mfma_f32_16x16x32_f16(A0l, Bh_##S[cf], aL[0][cf], 0, 0, 0); \
      aL[1][cf] = __builtin_amdgcn_mfma_f32_16x16x32_f16(A1h, Bl_##S[cf], aL[1][cf], 0, 0, 0); \
      aL[1][cf] = __builtin_amdgcn_mfma_f32_16x16x32_f16(A1l, Bh_##S[cf], aL[1][cf], 0, 0, 0); \
    }                                                                        \
  } while (0)

  // software pipeline: runtime loop (no full unroll) + sched_barrier(0)
  // pins load issue BEFORE the MFMA cluster -> dbuf must stay live.
  LOADB(a, 0);
  #pragma unroll 1
  for (int k0 = 0; k0 < 14; k0 += 2) {
    LOADB(b, k0 + 1);
    __builtin_amdgcn_sched_barrier(0);
    CVT(a);            // consumes loads issued one MFMA-cluster ago
    MFMAK(a);
    LOADB(a, k0 + 2);
    __builtin_amdgcn_sched_barrier(0);
    CVT(b);
    MFMAK(b);
  }
  LOADB(b, 15);
  __builtin_amdgcn_sched_barrier(0);
  CVT(a); MFMAK(a);
  CVT(b); MFMAK(b);
#undef LOADB
#undef CVT
#undef MFMAK

  // combine + bias -> lg. C/D: col = l15, row = l4*4 + e (HW-verified r4/r5).
  #pragma unroll
  for (int cf = 0; cf < 5; ++cf) {
    const int col = tr * 80 + cf * 16 + l15;
    const float bc = bias[g * CN + col];
    #pragma unroll
    for (int rf = 0; rf < 2; ++rf)
      #pragma unroll
      for (int e = 0; e < 4; ++e)
        lg[(rf * 16 + l4 * 4 + e) * LSTR + col] =
            aH[rf][cf][e] + aL[rf][cf][e] * (1.f / 512.f) + bc;
  }
  __syncthreads();

  // ---- verified epilogue (r3-r5) ----
  float pacc[5] = {0.f, 0.f, 0.f, 0.f, 0.f};
  #pragma unroll
  for (int i = 0; i < 8; ++i) {
    const int r = tr * 8 + i;
    const int n = m0 + r;
    const size_t grow = ((size_t)n * GN + g) * CN;
    float lv[5], gv[5];
    #pragma unroll
    for (int j = 0; j < 5; ++j) lv[j] = lg[r * LSTR + tc + 64 * j];
    #pragma unroll
    for (int j = 0; j < 5; ++j) gv[j] = gnoise[grow + tc + 64 * j];

    float bv = -3.4e38f; int bi = 1 << 30;
    #pragma unroll
    for (int j = 0; j < 5; ++j) {
      float v = lv[j] + gv[j];
      if (v > bv) { bv = v; bi = tc + 64 * j; }
    }
    for (int off = 1; off < 64; off <<= 1) {
      float ov = __shfl_xor(bv, off);
      int   oi = __shfl_xor(bi, off);
      if (ov > bv || (ov == bv && oi < bi)) { bv = ov; bi = oi; }
    }

    float mx = lv[0];
    #pragma unroll
    for (int j = 1; j < 5; ++j) mx = fmaxf(mx, lv[j]);
    for (int off = 1; off < 64; off <<= 1) mx = fmaxf(mx, __shfl_xor(mx, off));
    float e[5], s = 0.f;
    #pragma unroll
    for (int j = 0; j < 5; ++j) { e[j] = __expf(lv[j] - mx); s += e[j]; }
    for (int off = 1; off < 64; off <<= 1) s += __shfl_xor(s, off);
    const float inv = 1.f / s;
    const float mlt = (mask[n] != 0) ? 1.f : 0.f;
    #pragma unroll
    for (int j = 0; j < 5; ++j) pacc[j] += mlt * e[j] * inv;

    const float2* cvr = (const float2*)(cv + ((size_t)(g * CN + bi)) * DN);
    float2* o2 = (float2*)(out + (size_t)n * (GN * DN) + g * DN);
    o2[tc] = cvr[tc];
  }

  #pragma unroll
  for (int j = 0; j < 5; ++j) psum[tr * CN + tc + 64 * j] = pacc[j];
  __syncthreads();
  for (int c = tid; c < CN; c += NTHR) {
    float s = psum[c] + psum[CN + c] + psum[2 * CN + c] + psum[3 * CN + c];
    atomicAdd(&pp[g * CN + c], s);
  }
}

// ---------------- fp32 fallback (round-3 verified) ----------------
__global__ __launch_bounds__(NTHR) void k_main_fp32(
    const float* __restrict__ x, const int* __restrict__ mask,
    const float* __restrict__ gnoise, const float* __restrict__ W,
    const float* __restrict__ bias, const float* __restrict__ cv,
    float* __restrict__ out, float* __restrict__ pp)
{
  __shared__ __align__(16) char smem[47360];
  float* w_lds = (float*)smem;
  float* xs    = (float*)(smem + 42240);
  float* lg    = (float*)smem;
  float* psum  = (float*)(smem + 42240);

  const int m0  = blockIdx.x * BM;
  const int g   = blockIdx.y;
  const int tid = threadIdx.x;
  const int tc  = tid & 63;
  const int tr  = tid >> 6;
  const int r0  = tr * 8;

  float acc[8][5];
  #pragma unroll
  for (int i = 0; i < 8; ++i)
    #pragma unroll
    for (int j = 0; j < 5; ++j) acc[i][j] = 0.f;

  const float* Wg = W + (size_t)g * CN * HD;

  for (int k0 = 0; k0 < HD; k0 += 32) {
    __syncthreads();
    #pragma unroll
    for (int t = 0; t < 10; ++t) {
      int idx = tid + t * NTHR;
      int c   = idx >> 3;
      int k4  = idx & 7;
      float4 wv4 = *(const float4*)(Wg + (size_t)c * HD + k0 + k4 * 4);
      float* dst = &w_lds[c * WSTR + k4 * 4];
      dst[0] = wv4.x; dst[1] = wv4.y; dst[2] = wv4.z; dst[3] = wv4.w;
    }
    {
      int r = tid >> 3, k4 = tid & 7;
      float4 xv = *(const float4*)(x + (size_t)(m0 + r) * HD + k0 + k4 * 4);
      float* dst = &xs[r * 32 + k4 * 4];
      dst[0] = xv.x; dst[1] = xv.y; dst[2] = xv.z; dst[3] = xv.w;
    }
    __syncthreads();
    #pragma unroll
    for (int kk = 0; kk < 32; kk += 4) {
      float xq[8][4];
      #pragma unroll
      for (int i = 0; i < 8; ++i) {
        float4 t4 = *(const float4*)&xs[(r0 + i) * 32 + kk];
        xq[i][0] = t4.x; xq[i][1] = t4.y; xq[i][2] = t4.z; xq[i][3] = t4.w;
      }
      #pragma unroll
      for (int q = 0; q < 4; ++q) {
        float wv[5];
        #pragma unroll
        for (int j = 0; j < 5; ++j) wv[j] = w_lds[(tc + 64 * j) * WSTR + kk + q];
        #pragma unroll
        for (int i = 0; i < 8; ++i)
          #pragma unroll
          for (int j = 0; j < 5; ++j)
            acc[i][j] = fmaf(xq[i][q], wv[j], acc[i][j]);
      }
    }
  }
  __syncthreads();

  float bj[5];
  #pragma unroll
  for (int j = 0; j < 5; ++j) bj[j] = bias[g * CN + tc + 64 * j];
  #pragma unroll
  for (int i = 0; i < 8; ++i)
    #pragma unroll
    for (int j = 0; j < 5; ++j)
      lg[(r0 + i) * CN + tc + 64 * j] = acc[i][j] + bj[j];
  __syncthreads();

  float pacc[5] = {0.f, 0.f, 0.f, 0.f, 0.f};
  #pragma unroll
  for (int i = 0; i < 8; ++i) {
    const int r = r0 + i;
    const int n = m0 + r;
    const size_t grow = ((size_t)n * GN + g) * CN;
    float lv[5], gv[5];
    #pragma unroll
    for (int j = 0; j < 5; ++j) lv[j] = lg[r * CN + tc + 64 * j];
    #pragma unroll
    for (int j = 0; j < 5; ++j) gv[j] = gnoise[grow + tc + 64 * j];

    float bv = -3.4e38f; int bi = 1 << 30;
    #pragma unroll
    for (int j = 0; j < 5; ++j) {
      float v = lv[j] + gv[j];
      if (v > bv) { bv = v; bi = tc + 64 * j; }
    }
    for (int off = 1; off < 64; off <<= 1) {
      float ov = __shfl_xor(bv, off);
      int   oi = __shfl_xor(bi, off);
      if (ov > bv || (ov == bv && oi < bi)) { bv = ov; bi = oi; }
    }

    float mx = lv[0];
    #pragma unroll
    for (int j = 1; j < 5; ++j) mx = fmaxf(mx, lv[j]);
    for (int off = 1; off < 64; off <<= 1) mx = fmaxf(mx, __shfl_xor(mx, off));
    float e[5], s = 0.f;
    #pragma unroll
    for (int j = 0; j < 5; ++j) { e[j] = expf(lv[j] - mx); s += e[j]; }
    for (int off = 1; off < 64; off <<= 1) s += __shfl_xor(s, off);
    const float inv = 1.f / s;
    const float mlt = (mask[n] != 0) ? 1.f : 0.f;
    #pragma unroll
    for (int j = 0; j < 5; ++j) pacc[j] += mlt * e[j] * inv;

    const float2* cvr = (const float2*)(cv + ((size_t)(g * CN + bi)) * DN);
    float2* o2 = (float2*)(out + (size_t)n * (GN * DN) + g * DN);
    o2[tc] = cvr[tc];
  }

  #pragma unroll
  for (int j = 0; j < 5; ++j) psum[tr * CN + tc + 64 * j] = pacc[j];
  __syncthreads();
  for (int c = tid; c < CN; c += NTHR) {
    float s = psum[c] + psum[CN + c] + psum[2 * CN + c] + psum[3 * CN + c];
    atomicAdd(&pp[g * CN + c], s);
  }
}

// ---------------- perplexity finalize ----------------
__global__ __launch_bounds__(640) void k_final(
    const float* __restrict__ pp, const int* __restrict__ mask,
    float* __restrict__ out, int out_off)
{
  __shared__ float red[10];
  __shared__ float eL[GN * CN];
  __shared__ float perp_parts[GN];
  const int tid = threadIdx.x;

  float cnt = 0.f;
  for (int i = tid; i < TOKS; i += 640) cnt += (mask[i] != 0) ? 1.f : 0.f;
  for (int off = 1; off < 64; off <<= 1) cnt += __shfl_xor(cnt, off);
  if ((tid & 63) == 0) red[tid >> 6] = cnt;
  __syncthreads();
  float denom = 0.f;
  #pragma unroll
  for (int w = 0; w < 10; ++w) denom += red[w];
  denom = fmaxf(denom, 1.f);

  const float p = pp[tid] / denom;
  eL[tid] = p * logf(p + 1e-7f);
  __syncthreads();

  if (tid < 2 * 64) {
    const int gg = tid >> 6, ll = tid & 63;
    float s = 0.f;
    #pragma unroll
    for (int j = 0; j < 5; ++j) s += eL[gg * CN + ll + 64 * j];
    for (int off = 1; off < 64; off <<= 1) s += __shfl_xor(s, off);
    if (ll == 0) perp_parts[gg] = expf(-s);
  }
  __syncthreads();
  if (tid == 0) out[out_off] = perp_parts[0] + perp_parts[1];
}

extern "C" void kernel_launch(void* const* d_in, const int* in_sizes, int n_in,
                              void* d_out, int out_size, void* d_ws, size_t ws_size,
                              hipStream_t stream) {
  const float* x     = (const float*)d_in[0];
  const int*   mask  = (const int*)d_in[1];
  const float* gn    = (const float*)d_in[2];
  const float* W     = (const float*)d_in[3];
  const float* bias  = (const float*)d_in[4];
  const float* cv    = (const float*)d_in[5];
  float* out = (float*)d_out;
  float* pp  = (float*)d_ws;

  hipLaunchKernelGGL(k_zero, dim3(1), dim3(640), 0, stream, pp);

  if (ws_size >= WS_MID) {
    _Float16* wh = (_Float16*)((char*)d_ws + WS_W_OFF);
    _Float16* wl = wh + WS_WELEMS;
    hipLaunchKernelGGL(k_split, dim3((int)(WS_WELEMS / 8 / 256)), dim3(256), 0,
                       stream, W, wh, wl);
    hipLaunchKernelGGL(k_gemm_ep, dim3(TOKS / BM * GN), dim3(NTHR), 0, stream,
                       x, mask, gn, bias, cv, wh, wl, out, pp);
  } else {
    hipLaunchKernelGGL(k_main_fp32, dim3(TOKS / BM, GN), dim3(NTHR), 0, stream,
                       x, mask, gn, W, bias, cv, out, pp);
  }

  hipLaunchKernelGGL(k_final, dim3(1), dim3(640), 0, stream,
                     pp, mask, out, out_size - 1);
}

// Round 7
// 208.231 us; speedup vs baseline: 5.4613x; 1.1632x over previous
//
#include <hip/hip_runtime.h>
#include <hip/hip_bf16.h>
#include <math.h>

#define TOKS 49152   // B*T
#define HD   512     // hidden
#define GN   2       // groups
#define CN   320     // codes per group
#define DN   128     // code dim
#define BM   64      // tokens per block (main path)
#define NTHR 512     // 8 waves: 2 row-groups x 4 col-groups
#define LSTR 321     // lg row stride (f32): 2-way epilogue reads (free)
#define ASTR 36      // A LDS row stride (floats): 16B-aligned pad, 2-way banks
#define SB_L 20480   // byte offset of lo-B staging region (20 KB hi first)
#define SA   40960   // byte offset of A staging region (9216 B)
#define SMEM_SZ 51328

#define BMF  32      // fp32 fallback geometry (round-3 verified)
#define NTHRF 256
#define WSTR 33

#define WS_WELEMS ((size_t)(GN * CN) * HD)   // 327680
#define WS_W_OFF  4096
#define WS_MID    (WS_W_OFF + 4 * WS_WELEMS) // pp + wh + wl (~1.3 MB)

typedef _Float16 f16x8 __attribute__((ext_vector_type(8)));
typedef float    fx4   __attribute__((ext_vector_type(4)));

#define GLD_LDS16(gp, lp)                                                    \
  __builtin_amdgcn_global_load_lds(                                          \
      (const __attribute__((address_space(1))) void*)(gp),                   \
      (__attribute__((address_space(3))) void*)(lp), 16, 0, 0)

#define CVT8(U, V, HH, LL) do {                                              \
    _Pragma("unroll")                                                        \
    for (int e = 0; e < 4; ++e) {                                            \
      _Float16 h;                                                            \
      h = (_Float16)U[e]; HH[e] = h;                                         \
      LL[e] = (_Float16)((U[e] - (float)h) * 512.f);                         \
      h = (_Float16)V[e]; HH[e + 4] = h;                                     \
      LL[e + 4] = (_Float16)((V[e] - (float)h) * 512.f);                     \
    }                                                                        \
  } while (0)

// ---------------- zero the p-accumulator (fallback path) ----------------
__global__ void k_zero(float* pp) {
  int t = threadIdx.x;
  if (t < GN * CN) pp[t] = 0.f;
}

// -------- W fragment-major (hi, lo*512) f16 splitter + pp zero ----------
__global__ __launch_bounds__(256) void k_split(const float* __restrict__ src,
                                               _Float16* __restrict__ dh,
                                               _Float16* __restrict__ dl,
                                               float* __restrict__ pp) {
  if (blockIdx.x < 3) {
    int i = blockIdx.x * 256 + threadIdx.x;
    if (i < GN * CN) pp[i] = 0.f;
  }
  size_t t    = (size_t)blockIdx.x * 256 + threadIdx.x;
  int    lane = (int)(t & 63);
  size_t blob = t >> 6;
  int    k0   = (int)(blob & 15);
  size_t rb   = blob >> 4;
  const float* p = src + (rb * 16 + (lane & 15)) * HD + k0 * 32 + (lane >> 4) * 8;
  fx4 u = *(const fx4*)p;
  fx4 v = *(const fx4*)(p + 4);
  f16x8 h8, l8;
  #pragma unroll
  for (int e = 0; e < 4; ++e) {
    _Float16 hu = (_Float16)u[e], hv = (_Float16)v[e];
    h8[e]     = hu;
    h8[e + 4] = hv;
    l8[e]     = (_Float16)((u[e] - (float)hu) * 512.f);
    l8[e + 4] = (_Float16)((v[e] - (float)hv) * 512.f);
  }
  *(f16x8*)(dh + t * 8) = h8;
  *(f16x8*)(dl + t * 8) = l8;
}

// ---------------- fused MFMA GEMM + epilogue (LDS-staged) ----------------
// grid 1536; u -> mt=((u>>4)<<3)|(u&7), g=(u>>3)&1: the two g-twins of an
// m-tile land on the SAME XCD 8 dispatches apart -> x read L2-hits.
// Per K-step: B tile (320 cols x 32 k, h+l = 40 KB) staged by global_load_lds
// (5 instrs/wave, frag-major ws layout is LDS-linear); A (64x32 f32, 8 KB)
// reg-staged into pad-36 layout. All waves read frags from LDS -> no dup.
__global__ __launch_bounds__(NTHR, 4) void k_gemm_ep(
    const float* __restrict__ x, const int* __restrict__ mask,
    const float* __restrict__ gnoise, const float* __restrict__ bias,
    const float* __restrict__ cv, const _Float16* __restrict__ wh,
    const _Float16* __restrict__ wl, float* __restrict__ out,
    float* __restrict__ pp)
{
  __shared__ __align__(16) char smem[SMEM_SZ];
  float* As   = (float*)(smem + SA);      // [64][ASTR] f32 (GEMM phase)
  float* lg   = (float*)smem;             // [32][LSTR] f32 (epilogue, aliases B)
  float* psum = (float*)(smem + 41088);   // [8][CN]    (epilogue)

  const int u   = blockIdx.x;
  const int mt  = ((u >> 4) << 3) | (u & 7);
  const int g   = (u >> 3) & 1;
  const int m0  = mt * BM;
  const int tid = threadIdx.x;
  const int tc  = tid & 63;
  const int w   = tid >> 6;          // wave 0..7
  const int wr  = w >> 2;            // row-group 0..1 (32 rows)
  const int wc  = w & 3;             // col-group 0..3 (80 cols)
  const int l15 = tid & 15;
  const int l4  = tc >> 4;

  fx4 aH[2][5], aL[2][5];
  #pragma unroll
  for (int rf = 0; rf < 2; ++rf)
    #pragma unroll
    for (int cf = 0; cf < 5; ++cf) {
      aH[rf][cf] = (fx4){0.f, 0.f, 0.f, 0.f};
      aL[rf][cf] = (fx4){0.f, 0.f, 0.f, 0.f};
    }

  // B staging: wave w stages blobs w*5..w*5+4 (waves 0-3: hi, 4-7: lo;
  // 5 | 20 so no wave straddles). Blob cb holds cols (g*20+cb)*16..+16.
  const _Float16* bb = (w < 4) ? wh : wl;
  const int cb0      = (w < 4) ? w * 5 : w * 5 - 20;
  const _Float16* bsrc = bb + (size_t)(g * 20 + cb0) * 8192 + (size_t)tc * 8;
  char* bdst = smem + (size_t)(w * 5) * 1024;
  // A staging: wave w covers rows w*8..w*8+7, lane = (row, 16B-chunk)
  const int ar = w * 8 + (tc >> 3);
  const int ac = tc & 7;
  const float* asrc = x + (size_t)(m0 + ar) * HD + ac * 4;
  float* adst = &As[ar * ASTR + ac * 4];

  #pragma unroll 1
  for (int t = 0; t < 16; ++t) {
    __syncthreads();                       // staging buffer free
    fx4 av = *(const fx4*)(asrc + t * 32); // A global->reg
    #pragma unroll
    for (int q = 0; q < 5; ++q)            // B global->LDS async
      GLD_LDS16(bsrc + (size_t)q * 8192 + (size_t)t * 512, bdst + q * 1024);
    *(fx4*)adst = av;                      // A reg->LDS (padded)
    __syncthreads();                       // all staged (drains vmcnt)

    // A fragments from LDS + in-register split (r4-verified math)
    const float* a0p = &As[(wr * 32 + l15) * ASTR + l4 * 8];
    fx4 u0 = *(const fx4*)a0p;
    fx4 v0 = *(const fx4*)(a0p + 4);
    fx4 u1 = *(const fx4*)(a0p + 16 * ASTR);
    fx4 v1 = *(const fx4*)(a0p + 16 * ASTR + 4);
    f16x8 A0h, A0l, A1h, A1l;
    CVT8(u0, v0, A0h, A0l);
    CVT8(u1, v1, A1h, A1l);
    #pragma unroll
    for (int cf = 0; cf < 5; ++cf) {
      f16x8 Bh = *(const f16x8*)(smem + (wc * 5 + cf) * 1024 + tc * 16);
      f16x8 Bl = *(const f16x8*)(smem + SB_L + (wc * 5 + cf) * 1024 + tc * 16);
      aH[0][cf] = __builtin_amdgcn_mfma_f32_16x16x32_f16(A0h, Bh, aH[0][cf], 0, 0, 0);
      aH[1][cf] = __builtin_amdgcn_mfma_f32_16x16x32_f16(A1h, Bh, aH[1][cf], 0, 0, 0);
      aL[0][cf] = __builtin_amdgcn_mfma_f32_16x16x32_f16(A0h, Bl, aL[0][cf], 0, 0, 0);
      aL[0][cf] = __builtin_amdgcn_mfma_f32_16x16x32_f16(A0l, Bh, aL[0][cf], 0, 0, 0);
      aL[1][cf] = __builtin_amdgcn_mfma_f32_16x16x32_f16(A1h, Bl, aL[1][cf], 0, 0, 0);
      aL[1][cf] = __builtin_amdgcn_mfma_f32_16x16x32_f16(A1l, Bh, aL[1][cf], 0, 0, 0);
    }
  }
  __syncthreads();   // staging region dead; lg may now alias it

  float bj[5];
  #pragma unroll
  for (int cf = 0; cf < 5; ++cf) bj[cf] = bias[g * CN + wc * 80 + cf * 16 + l15];

  // two 32-row epilogue phases (lg = 41 KB fits only half the tile)
  float pacc[5] = {0.f, 0.f, 0.f, 0.f, 0.f};
  #pragma unroll
  for (int p = 0; p < 2; ++p) {
    if (wr == p) {
      // C/D layout (HW-verified r4-r6): col = l15, row = l4*4 + e
      #pragma unroll
      for (int cf = 0; cf < 5; ++cf) {
        const int col = wc * 80 + cf * 16 + l15;
        #pragma unroll
        for (int rf = 0; rf < 2; ++rf)
          #pragma unroll
          for (int e = 0; e < 4; ++e)
            lg[(rf * 16 + l4 * 4 + e) * LSTR + col] =
                aH[rf][cf][e] + aL[rf][cf][e] * (1.f / 512.f) + bj[cf];
      }
    }
    __syncthreads();
    // all 8 waves: 4 rows each (verified row epilogue, r3-r6)
    #pragma unroll
    for (int i = 0; i < 4; ++i) {
      const int rl = w * 4 + i;
      const int n  = m0 + p * 32 + rl;
      const size_t grow = ((size_t)n * GN + g) * CN;
      float lv[5], gv[5];
      #pragma unroll
      for (int j = 0; j < 5; ++j) lv[j] = lg[rl * LSTR + tc + 64 * j];
      #pragma unroll
      for (int j = 0; j < 5; ++j) gv[j] = gnoise[grow + tc + 64 * j];

      float bv = -3.4e38f; int bi = 1 << 30;
      #pragma unroll
      for (int j = 0; j < 5; ++j) {
        float v = lv[j] + gv[j];
        if (v > bv) { bv = v; bi = tc + 64 * j; }
      }
      for (int off = 1; off < 64; off <<= 1) {
        float ov = __shfl_xor(bv, off);
        int   oi = __shfl_xor(bi, off);
        if (ov > bv || (ov == bv && oi < bi)) { bv = ov; bi = oi; }
      }

      float mx = lv[0];
      #pragma unroll
      for (int j = 1; j < 5; ++j) mx = fmaxf(mx, lv[j]);
      for (int off = 1; off < 64; off <<= 1) mx = fmaxf(mx, __shfl_xor(mx, off));
      float e[5], s = 0.f;
      #pragma unroll
      for (int j = 0; j < 5; ++j) { e[j] = __expf(lv[j] - mx); s += e[j]; }
      for (int off = 1; off < 64; off <<= 1) s += __shfl_xor(s, off);
      const float inv = 1.f / s;
      const float mlt = (mask[n] != 0) ? 1.f : 0.f;
      #pragma unroll
      for (int j = 0; j < 5; ++j) pacc[j] += mlt * e[j] * inv;

      const float2* cvr = (const float2*)(cv + ((size_t)(g * CN + bi)) * DN);
      float2* o2 = (float2*)(out + (size_t)n * (GN * DN) + g * DN);
      o2[tc] = cvr[tc];
    }
    __syncthreads();   // lg free for next phase
  }

  #pragma unroll
  for (int j = 0; j < 5; ++j) psum[w * CN + tc + 64 * j] = pacc[j];
  __syncthreads();
  for (int c = tid; c < CN; c += NTHR) {
    float s = 0.f;
    #pragma unroll
    for (int q = 0; q < 8; ++q) s += psum[q * CN + c];
    atomicAdd(&pp[g * CN + c], s);
  }
}

// ---------------- fp32 fallback (round-3 verified, BMF=32) ----------------
__global__ __launch_bounds__(NTHRF) void k_main_fp32(
    const float* __restrict__ x, const int* __restrict__ mask,
    const float* __restrict__ gnoise, const float* __restrict__ W,
    const float* __restrict__ bias, const float* __restrict__ cv,
    float* __restrict__ out, float* __restrict__ pp)
{
  __shared__ __align__(16) char smem[47360];
  float* w_lds = (float*)smem;
  float* xs    = (float*)(smem + 42240);
  float* lg    = (float*)smem;
  float* psum  = (float*)(smem + 42240);

  const int m0  = blockIdx.x * BMF;
  const int g   = blockIdx.y;
  const int tid = threadIdx.x;
  const int tc  = tid & 63;
  const int tr  = tid >> 6;
  const int r0  = tr * 8;

  float acc[8][5];
  #pragma unroll
  for (int i = 0; i < 8; ++i)
    #pragma unroll
    for (int j = 0; j < 5; ++j) acc[i][j] = 0.f;

  const float* Wg = W + (size_t)g * CN * HD;

  for (int k0 = 0; k0 < HD; k0 += 32) {
    __syncthreads();
    #pragma unroll
    for (int t = 0; t < 10; ++t) {
      int idx = tid + t * NTHRF;
      int c   = idx >> 3;
      int k4  = idx & 7;
      float4 wv4 = *(const float4*)(Wg + (size_t)c * HD + k0 + k4 * 4);
      float* dst = &w_lds[c * WSTR + k4 * 4];
      dst[0] = wv4.x; dst[1] = wv4.y; dst[2] = wv4.z; dst[3] = wv4.w;
    }
    {
      int r = tid >> 3, k4 = tid & 7;
      float4 xv = *(const float4*)(x + (size_t)(m0 + r) * HD + k0 + k4 * 4);
      float* dst = &xs[r * 32 + k4 * 4];
      dst[0] = xv.x; dst[1] = xv.y; dst[2] = xv.z; dst[3] = xv.w;
    }
    __syncthreads();
    #pragma unroll
    for (int kk = 0; kk < 32; kk += 4) {
      float xq[8][4];
      #pragma unroll
      for (int i = 0; i < 8; ++i) {
        float4 t4 = *(const float4*)&xs[(r0 + i) * 32 + kk];
        xq[i][0] = t4.x; xq[i][1] = t4.y; xq[i][2] = t4.z; xq[i][3] = t4.w;
      }
      #pragma unroll
      for (int q = 0; q < 4; ++q) {
        float wv[5];
        #pragma unroll
        for (int j = 0; j < 5; ++j) wv[j] = w_lds[(tc + 64 * j) * WSTR + kk + q];
        #pragma unroll
        for (int i = 0; i < 8; ++i)
          #pragma unroll
          for (int j = 0; j < 5; ++j)
            acc[i][j] = fmaf(xq[i][q], wv[j], acc[i][j]);
      }
    }
  }
  __syncthreads();

  float bj[5];
  #pragma unroll
  for (int j = 0; j < 5; ++j) bj[j] = bias[g * CN + tc + 64 * j];
  #pragma unroll
  for (int i = 0; i < 8; ++i)
    #pragma unroll
    for (int j = 0; j < 5; ++j)
      lg[(r0 + i) * CN + tc + 64 * j] = acc[i][j] + bj[j];
  __syncthreads();

  float pacc[5] = {0.f, 0.f, 0.f, 0.f, 0.f};
  #pragma unroll
  for (int i = 0; i < 8; ++i) {
    const int r = r0 + i;
    const int n = m0 + r;
    const size_t grow = ((size_t)n * GN + g) * CN;
    float lv[5], gv[5];
    #pragma unroll
    for (int j = 0; j < 5; ++j) lv[j] = lg[r * CN + tc + 64 * j];
    #pragma unroll
    for (int j = 0; j < 5; ++j) gv[j] = gnoise[grow + tc + 64 * j];

    float bv = -3.4e38f; int bi = 1 << 30;
    #pragma unroll
    for (int j = 0; j < 5; ++j) {
      float v = lv[j] + gv[j];
      if (v > bv) { bv = v; bi = tc + 64 * j; }
    }
    for (int off = 1; off < 64; off <<= 1) {
      float ov = __shfl_xor(bv, off);
      int   oi = __shfl_xor(bi, off);
      if (ov > bv || (ov == bv && oi < bi)) { bv = ov; bi = oi; }
    }

    float mx = lv[0];
    #pragma unroll
    for (int j = 1; j < 5; ++j) mx = fmaxf(mx, lv[j]);
    for (int off = 1; off < 64; off <<= 1) mx = fmaxf(mx, __shfl_xor(mx, off));
    float e[5], s = 0.f;
    #pragma unroll
    for (int j = 0; j < 5; ++j) { e[j] = expf(lv[j] - mx); s += e[j]; }
    for (int off = 1; off < 64; off <<= 1) s += __shfl_xor(s, off);
    const float inv = 1.f / s;
    const float mlt = (mask[n] != 0) ? 1.f : 0.f;
    #pragma unroll
    for (int j = 0; j < 5; ++j) pacc[j] += mlt * e[j] * inv;

    const float2* cvr = (const float2*)(cv + ((size_t)(g * CN + bi)) * DN);
    float2* o2 = (float2*)(out + (size_t)n * (GN * DN) + g * DN);
    o2[tc] = cvr[tc];
  }

  #pragma unroll
  for (int j = 0; j < 5; ++j) psum[tr * CN + tc + 64 * j] = pacc[j];
  __syncthreads();
  for (int c = tid; c < CN; c += NTHRF) {
    float s = psum[c] + psum[CN + c] + psum[2 * CN + c] + psum[3 * CN + c];
    atomicAdd(&pp[g * CN + c], s);
  }
}

// ---------------- perplexity finalize ----------------
__global__ __launch_bounds__(640) void k_final(
    const float* __restrict__ pp, const int* __restrict__ mask,
    float* __restrict__ out, int out_off)
{
  __shared__ float red[10];
  __shared__ float eL[GN * CN];
  __shared__ float perp_parts[GN];
  const int tid = threadIdx.x;

  float cnt = 0.f;
  for (int i = tid; i < TOKS; i += 640) cnt += (mask[i] != 0) ? 1.f : 0.f;
  for (int off = 1; off < 64; off <<= 1) cnt += __shfl_xor(cnt, off);
  if ((tid & 63) == 0) red[tid >> 6] = cnt;
  __syncthreads();
  float denom = 0.f;
  #pragma unroll
  for (int w = 0; w < 10; ++w) denom += red[w];
  denom = fmaxf(denom, 1.f);

  const float p = pp[tid] / denom;
  eL[tid] = p * logf(p + 1e-7f);
  __syncthreads();

  if (tid < 2 * 64) {
    const int gg = tid >> 6, ll = tid & 63;
    float s = 0.f;
    #pragma unroll
    for (int j = 0; j < 5; ++j) s += eL[gg * CN + ll + 64 * j];
    for (int off = 1; off < 64; off <<= 1) s += __shfl_xor(s, off);
    if (ll == 0) perp_parts[gg] = expf(-s);
  }
  __syncthreads();
  if (tid == 0) out[out_off] = perp_parts[0] + perp_parts[1];
}

extern "C" void kernel_launch(void* const* d_in, const int* in_sizes, int n_in,
                              void* d_out, int out_size, void* d_ws, size_t ws_size,
                              hipStream_t stream) {
  const float* x     = (const float*)d_in[0];
  const int*   mask  = (const int*)d_in[1];
  const float* gn    = (const float*)d_in[2];
  const float* W     = (const float*)d_in[3];
  const float* bias  = (const float*)d_in[4];
  const float* cv    = (const float*)d_in[5];
  float* out = (float*)d_out;
  float* pp  = (float*)d_ws;

  if (ws_size >= WS_MID) {
    _Float16* wh = (_Float16*)((char*)d_ws + WS_W_OFF);
    _Float16* wl = wh + WS_WELEMS;
    hipLaunchKernelGGL(k_split, dim3((int)(WS_WELEMS / 8 / 256)), dim3(256), 0,
                       stream, W, wh, wl, pp);
    hipLaunchKernelGGL(k_gemm_ep, dim3(TOKS / BM * GN), dim3(NTHR), 0, stream,
                       x, mask, gn, bias, cv, wh, wl, out, pp);
  } else {
    hipLaunchKernelGGL(k_zero, dim3(1), dim3(640), 0, stream, pp);
    hipLaunchKernelGGL(k_main_fp32, dim3(TOKS / BMF, GN), dim3(NTHRF), 0, stream,
                       x, mask, gn, W, bias, cv, out, pp);
  }

  hipLaunchKernelGGL(k_final, dim3(1), dim3(640), 0, stream,
                     pp, mask, out, out_size - 1);
}